// Round 5
// baseline (427.626 us; speedup 1.0000x reference)
//
#include <hip/hip_runtime.h>

// SparseConv2d N=32, OC=IC=256, H=W=56, K=3, pad=1 -> dense bf16 MFMA implicit GEMM
constexpr int NB=32, ICC=256, OCC=256, HH=56, WW=56;
constexpr int HW=HH*WW, CHW=ICC*HW;
constexpr int YT=14, MT=2;
constexpr int LROW=58;           // 56 cols + 2 halo
constexpr int PAD=40;            // ushorts per (r,c) slot: 32 data + 8 pad -> 80 B, 16B-aligned
constexpr int LDS_ELEMS=6*LROW*PAD;   // 13920 ushort = 27840 B

using short8  = __attribute__((ext_vector_type(8))) short;   // 8 x bf16 bits (A/B frag)
using f32x4   = __attribute__((ext_vector_type(4))) float;   // C/D frag

__device__ inline unsigned bf16rne(float x){
  unsigned u = __float_as_uint(x);
  return (u + 0x7fffu + ((u>>16)&1u)) >> 16;   // round-to-nearest-even
}

// wb[j][oc][ic] bf16, j = kh*3+kw, masked weights. 1.18 MB in d_ws.
__global__ __launch_bounds__(256) void pack_weights(
    const float* __restrict__ w, const int* __restrict__ mask,
    unsigned short* __restrict__ wb){
  const int oc = blockIdx.x, ic = threadIdx.x;
  const int base = (oc*ICC + ic)*9;
  #pragma unroll
  for (int j=0;j<9;++j){
    float v = (mask[base+j] != 0) ? w[base+j] : 0.f;
    wb[(j*OCC + oc)*ICC + ic] = (unsigned short)bf16rne(v);
  }
}

__global__ __launch_bounds__(256,3) void conv_mfma(
    const float* __restrict__ in, const unsigned short* __restrict__ wb,
    const float* __restrict__ bias, float* __restrict__ out){
  __shared__ unsigned short xt[LDS_ELEMS];   // [6 rows][58 cols][40 ic-slots]

  // XCD-aware decode: lid&7 = XCD residue -> each XCD sees only 4 of 32 batches
  const int lid  = blockIdx.x;
  const int xcd  = lid & 7, slot = lid >> 3;          // 112 slots per residue
  const int ngrp = slot / 28, rem = slot - ngrp*28;   // same-n blocks adjacent
  const int mt   = rem / 14,  yt  = rem - mt*14;
  const int n    = xcd + 8*ngrp;
  const int y0   = yt*4, ocb = mt*128;

  const int tid  = threadIdx.x;
  const int lane = tid & 63, wv = tid >> 6;
  const int q    = lane >> 4, l16 = lane & 15;

  // zero LDS once: halo cells (c=0, c=57, skipped rows) stay zero for all chunks
  for (int i = tid; i < LDS_ELEMS/2; i += 256) ((unsigned*)xt)[i] = 0u;

  // wave tile: 64 ocs x 112 px (4 x 7 MFMA tiles of 16x16)
  const int ocw = ocb + (wv & 1)*64;
  const int pxw = (wv >> 1)*112;

  int pbase[7];
  #pragma unroll
  for (int p=0;p<7;++p){
    int px = pxw + p*16 + l16;          // pixel within 4x56 tile (row-crossing OK)
    int yl = px / 56, x = px - yl*56;
    pbase[p] = (yl*LROW + x)*(PAD*2) + q*16;   // 16B-aligned LDS byte addr
  }

  f32x4 acc[4][7];
  #pragma unroll
  for (int s=0;s<4;++s)
    #pragma unroll
    for (int p=0;p<7;++p) acc[s][p] = (f32x4){0.f,0.f,0.f,0.f};

  const int rskipA = (yt==0)      ? 0 : -1;   // input row y0-1 invalid
  const int rskipB = (yt==YT-1)   ? 5 : -1;   // input row y0+4 invalid

  __syncthreads();   // zeroing complete before first staging

  for (int ch=0; ch<8; ++ch){
    const int ic0 = ch*32;

    // ---- stage 32 ics x 6 rows x 56 cols fp32->bf16 into LDS ----
    // item idx = (r*16 + icp)*14 + xg, xg FASTEST: 14 consecutive lanes read a
    // contiguous 224B row-run (coalesced); one item in flight (register economy).
    #pragma unroll
    for (int i=0;i<6;++i){
      int idx = tid + i*256;
      if (idx < 1344){
        int xg = idx % 14;
        int t  = idx / 14;
        int icp = t & 15, r = t >> 4;
        if (r != rskipA && r != rskipB){
          int y = y0 - 1 + r;
          const float* gp = in + n*CHW + (ic0 + icp*2)*HW + y*WW + xg*4;
          float4 g0 = *(const float4*)gp;          // ic plane
          float4 g1 = *(const float4*)(gp + HW);   // ic+1 plane
          unsigned w0 = bf16rne(g0.x) | (bf16rne(g1.x)<<16);
          unsigned w1 = bf16rne(g0.y) | (bf16rne(g1.y)<<16);
          unsigned w2 = bf16rne(g0.z) | (bf16rne(g1.z)<<16);
          unsigned w3 = bf16rne(g0.w) | (bf16rne(g1.w)<<16);
          unsigned* dp = (unsigned*)xt + (r*LROW + 1 + xg*4)*(PAD/2) + icp;
          dp[0]           = w0;          // cols c..c+3, ic pair packed per dword
          dp[PAD/2]       = w1;
          dp[PAD]         = w2;
          dp[3*(PAD/2)]   = w3;
        }
      }
    }
    __syncthreads();

    // ---- K-slice: 9 offsets x 32 ics of MFMA ----
    #pragma unroll
    for (int kh=0;kh<3;++kh){
      #pragma unroll
      for (int kw=0;kw<3;++kw){
        const int j = kh*3 + kw;
        // A-frags: one contiguous 16B global load per oc-subtile (L2-resident wb)
        const unsigned short* wp = wb + (j*OCC + ocw + l16)*ICC + ic0 + q*8;
        short8 a0 = *(const short8*)(wp          );
        short8 a1 = *(const short8*)(wp + 16*ICC );
        short8 a2 = *(const short8*)(wp + 32*ICC );
        short8 a3 = *(const short8*)(wp + 48*ICC );
        const int doff = (kh*LROW + kw)*(PAD*2);   // multiple of 80; +pbase stays 16B-aligned
        #pragma unroll
        for (int p=0;p<7;++p){
          const short8 b = *(const short8*)((const char*)xt + pbase[p] + doff); // ds_read_b128
          acc[0][p] = __builtin_amdgcn_mfma_f32_16x16x32_bf16(a0, b, acc[0][p], 0,0,0);
          acc[1][p] = __builtin_amdgcn_mfma_f32_16x16x32_bf16(a1, b, acc[1][p], 0,0,0);
          acc[2][p] = __builtin_amdgcn_mfma_f32_16x16x32_bf16(a2, b, acc[2][p], 0,0,0);
          acc[3][p] = __builtin_amdgcn_mfma_f32_16x16x32_bf16(a3, b, acc[3][p], 0,0,0);
        }
      }
    }
    __syncthreads();
  }

  // ---- epilogue: D row = oc (quad*4+reg), col = px (lane&15)  [m89 layout] ----
  #pragma unroll
  for (int s=0;s<4;++s){
    const int oc4 = ocw + s*16 + q*4;
    float4 bv = *(const float4*)(bias + oc4);
    #pragma unroll
    for (int i=0;i<4;++i){
      const float bb = (i==0)?bv.x:(i==1)?bv.y:(i==2)?bv.z:bv.w;
      float* op = out + (n*OCC + oc4 + i)*HW + y0*WW + pxw + l16;
      #pragma unroll
      for (int p=0;p<7;++p){
        op[p*16] = acc[s][p][i] + bb;
      }
    }
  }
}

extern "C" void kernel_launch(void* const* d_in, const int* in_sizes, int n_in,
                              void* d_out, int out_size, void* d_ws, size_t ws_size,
                              hipStream_t stream) {
  const float* in   = (const float*)d_in[0];
  const float* w    = (const float*)d_in[1];
  const float* bias = (const float*)d_in[2];
  const int*   mask = (const int*)d_in[3];
  float*       out  = (float*)d_out;
  unsigned short* wb = (unsigned short*)d_ws;   // 9*256*256*2 B = 1.18 MB

  pack_weights<<<OCC, 256, 0, stream>>>(w, mask, wb);
  conv_mfma<<<8*4*MT*YT, 256, 0, stream>>>(in, wb, bias, out);  // 896 blocks
}